// Round 16
// baseline (321.881 us; speedup 1.0000x reference)
//
#include <hip/hip_runtime.h>

#define NNODES 100000
#define NEDGES 625000
#define DFEAT  128
#define NGRAPH 256
#define DOUTC  10
#define NBINS  64

typedef __attribute__((ext_vector_type(8))) short bf16x8;
typedef __attribute__((ext_vector_type(4))) float f32x4;
typedef __attribute__((ext_vector_type(8))) ushort ushort8v;

__device__ __forceinline__ ushort f2bf(float f) {
    __bf16 b = (__bf16)f;
    return __builtin_bit_cast(ushort, b);
}
__device__ __forceinline__ float bf2f(ushort u) {
    return __builtin_bit_cast(float, (uint)u << 16);
}

// ---------------------------------------------------------------------------
// convert_all: weights->bf16, x->bf16, zero gsum/deg/counter/binCnt
// ---------------------------------------------------------------------------
__global__ __launch_bounds__(256) void convert_all(const float* __restrict__ x,
                                                   const float* __restrict__ w0,
                                                   const float* __restrict__ w1,
                                                   const float* __restrict__ w2,
                                                   const float* __restrict__ w3,
                                                   const float* __restrict__ w4,
                                                   const float* __restrict__ w5,
                                                   ushort* __restrict__ Wb,
                                                   ushort* __restrict__ Hb,
                                                   float* __restrict__ gsum,
                                                   int* __restrict__ deg,
                                                   int* __restrict__ counter,
                                                   int* __restrict__ binCnt) {
    const int tid = blockIdx.x * 256 + threadIdx.x;
    const int NT = gridDim.x * 256;
    if (tid == 0) *counter = 0;
    if (tid < NBINS) binCnt[tid] = 0;
    const float* ptrs[6] = {w0, w1, w2, w3, w4, w5};
    for (int i = tid; i < 6 * DFEAT * DFEAT; i += NT) {
        int m = i >> 14, j = i & 16383;
        Wb[i] = f2bf(ptrs[m][j]);
    }
    for (int i = tid; i < NGRAPH * DFEAT; i += NT) gsum[i] = 0.f;
    for (int i = tid; i < NNODES; i += NT) deg[i] = 0;
    const int n8 = NNODES * DFEAT / 8;
    for (int i = tid; i < n8; i += NT) {
        float4 a = *(const float4*)&x[(size_t)i * 8];
        float4 b = *(const float4*)&x[(size_t)i * 8 + 4];
        ushort8v o;
        o[0] = f2bf(a.x); o[1] = f2bf(a.y); o[2] = f2bf(a.z); o[3] = f2bf(a.w);
        o[4] = f2bf(b.x); o[5] = f2bf(b.y); o[6] = f2bf(b.z); o[7] = f2bf(b.w);
        *(ushort8v*)&Hb[(size_t)i * 8] = o;
    }
}

// ---------------------------------------------------------------------------
// CSR build, scan-free (proven R10)
// ---------------------------------------------------------------------------
__global__ __launch_bounds__(256) void histo_kernel(const int* __restrict__ rows,
                                                    int* __restrict__ deg) {
    int i = blockIdx.x * 256 + threadIdx.x;
    if (i < NEDGES) atomicAdd(&deg[rows[i]], 1);
}

__global__ __launch_bounds__(256) void alloc_ranges(const int* __restrict__ deg,
                                                    int* __restrict__ offs,
                                                    int* __restrict__ cursor,
                                                    int* __restrict__ counter) {
    __shared__ int red[256];
    __shared__ int baseSh;
    int t = threadIdx.x;
    int i = blockIdx.x * 256 + t;
    int v = (i < NNODES) ? deg[i] : 0;
    red[t] = v;
    __syncthreads();
    int x = v;
    for (int off = 1; off < 256; off <<= 1) {
        int y = (t >= off) ? red[t - off] : 0;
        __syncthreads();
        x += y;
        red[t] = x;
        __syncthreads();
    }
    if (t == 255) baseSh = atomicAdd(counter, x);
    __syncthreads();
    int pos = baseSh + x - v;
    if (i < NNODES) { offs[i] = pos; cursor[i] = pos; }
}

__global__ __launch_bounds__(256) void scatter_edges(const int* __restrict__ rows,
                                                     const int* __restrict__ cols,
                                                     int* __restrict__ cursor,
                                                     int* __restrict__ scol) {
    int i = blockIdx.x * 256 + threadIdx.x;
    if (i < NEDGES) {
        int p = atomicAdd(&cursor[rows[i]], 1);
        scol[p] = cols[i];
    }
}

// ---------------------------------------------------------------------------
// Degree binning: counting sort of nodes by min(deg,63) -> perm[].
// Waves in the aggregate then process 4 similar-degree nodes -> no lockstep
// divergence waste (E[max of 4 Poisson] ~9-10 vs mean 6.25).
// ---------------------------------------------------------------------------
__global__ __launch_bounds__(256) void bin_count(const int* __restrict__ deg,
                                                 int* __restrict__ binCnt) {
    __shared__ int l[NBINS];
    int t = threadIdx.x;
    if (t < NBINS) l[t] = 0;
    __syncthreads();
    int i = blockIdx.x * 256 + t;
    if (i < NNODES) atomicAdd(&l[min(deg[i], NBINS - 1)], 1);
    __syncthreads();
    if (t < NBINS && l[t]) atomicAdd(&binCnt[t], l[t]);
}

__global__ __launch_bounds__(64) void bin_scan(const int* __restrict__ binCnt,
                                               int* __restrict__ binCursor) {
    if (threadIdx.x == 0) {
        int run = 0;
        for (int i = 0; i < NBINS; ++i) { binCursor[i] = run; run += binCnt[i]; }
    }
}

__global__ __launch_bounds__(256) void build_perm(const int* __restrict__ deg,
                                                  int* __restrict__ binCursor,
                                                  int* __restrict__ perm) {
    __shared__ int lcnt[NBINS], lbase[NBINS];
    int t = threadIdx.x;
    if (t < NBINS) lcnt[t] = 0;
    __syncthreads();
    int i = blockIdx.x * 256 + t;
    int d = -1;
    if (i < NNODES) { d = min(deg[i], NBINS - 1); atomicAdd(&lcnt[d], 1); }
    __syncthreads();
    if (t < NBINS) { lbase[t] = lcnt[t] ? atomicAdd(&binCursor[t], lcnt[t]) : 0; lcnt[t] = 0; }
    __syncthreads();
    if (i < NNODES) {
        int r = atomicAdd(&lcnt[d], 1);
        perm[lbase[d] + r] = i;
    }
}

// ---------------------------------------------------------------------------
// Aggregate in H-space (R13 body + degree-binned node order): 16-lane group
// per node, 4 edge-rows in flight, 256 B coalesced row reads. Edge order
// within a node unchanged -> per-output math identical.
// ---------------------------------------------------------------------------
__global__ __launch_bounds__(256) void aggregate_g16(const ushort* __restrict__ Hb,
                                                     const int* __restrict__ offs,
                                                     const int* __restrict__ deg,
                                                     const int* __restrict__ scol,
                                                     const int* __restrict__ perm,
                                                     ushort* __restrict__ Ab) {
    int idx = blockIdx.x * 16 + (threadIdx.x >> 4);
    int l = threadIdx.x & 15;
    if (idx >= NNODES) return;
    int node = perm[idx];
    int beg = offs[node];
    int end = beg + deg[node];
    float a[8] = {};
    int e = beg;
    for (; e + 4 <= end; e += 4) {
        int c0 = scol[e];
        int c1 = scol[e + 1];
        int c2 = scol[e + 2];
        int c3 = scol[e + 3];
        ushort8v v0 = *(const ushort8v*)&Hb[(size_t)c0 * DFEAT + l * 8];
        ushort8v v1 = *(const ushort8v*)&Hb[(size_t)c1 * DFEAT + l * 8];
        ushort8v v2 = *(const ushort8v*)&Hb[(size_t)c2 * DFEAT + l * 8];
        ushort8v v3 = *(const ushort8v*)&Hb[(size_t)c3 * DFEAT + l * 8];
#pragma unroll
        for (int j = 0; j < 8; ++j)
            a[j] += (bf2f(v0[j]) + bf2f(v1[j])) + (bf2f(v2[j]) + bf2f(v3[j]));
    }
    for (; e < end; ++e) {
        int c0 = scol[e];
        ushort8v v0 = *(const ushort8v*)&Hb[(size_t)c0 * DFEAT + l * 8];
#pragma unroll
        for (int j = 0; j < 8; ++j) a[j] += bf2f(v0[j]);
    }
    ushort8v o;
#pragma unroll
    for (int j = 0; j < 8; ++j) o[j] = f2bf(a[j]);
    *(ushort8v*)&Ab[(size_t)node * DFEAT + l * 8] = o;
}

// ---------------------------------------------------------------------------
// Fused layer GEMM, quarter-split + reg-pinned weights (proven R15)
// ---------------------------------------------------------------------------
__global__ __launch_bounds__(256, 4) void fused_dual_gemm_q(const ushort* __restrict__ Hin,
                                                            const ushort* __restrict__ Ab,
                                                            const ushort* __restrict__ W1b,
                                                            const ushort* __restrict__ W2b,
                                                            ushort* __restrict__ Hout) {
    int wid = threadIdx.x >> 6;              // out-quarter 0..3
    int lane = threadIdx.x & 63;
    int l15 = lane & 15, lhi = lane >> 4;

    bf16x8 w1[2][4], w2[2][4];
#pragma unroll
    for (int ot = 0; ot < 2; ++ot)
#pragma unroll
        for (int ks = 0; ks < 4; ++ks) {
            int orow = wid * 32 + ot * 16 + l15;
            w1[ot][ks] = *(const bf16x8*)&W1b[orow * DFEAT + ks * 32 + lhi * 8];
            w2[ot][ks] = *(const bf16x8*)&W2b[orow * DFEAT + ks * 32 + lhi * 8];
        }
#pragma unroll
    for (int ot = 0; ot < 2; ++ot)
#pragma unroll
        for (int ks = 0; ks < 4; ++ks) {
            asm volatile("" : "+v"(w1[ot][ks]));
            asm volatile("" : "+v"(w2[ot][ks]));
        }

    const int ntiles = NNODES / 16;              // 6250
    for (int t = blockIdx.x; t < ntiles; t += gridDim.x) {
        size_t rowOff = (size_t)(t * 16 + l15) * DFEAT;
        bf16x8 hfr[4], afr[4];
#pragma unroll
        for (int ks = 0; ks < 4; ++ks) {
            hfr[ks] = *(const bf16x8*)&Hin[rowOff + ks * 32 + lhi * 8];
            afr[ks] = *(const bf16x8*)&Ab[rowOff + ks * 32 + lhi * 8];
        }
#pragma unroll
        for (int ot = 0; ot < 2; ++ot) {
            f32x4 acc = {};
#pragma unroll
            for (int ks = 0; ks < 4; ++ks)
                acc = __builtin_amdgcn_mfma_f32_16x16x32_bf16(w1[ot][ks], hfr[ks], acc, 0, 0, 0);
#pragma unroll
            for (int ks = 0; ks < 4; ++ks)
                acc = __builtin_amdgcn_mfma_f32_16x16x32_bf16(w2[ot][ks], afr[ks], acc, 0, 0, 0);
            ushort4 p;
            p.x = f2bf(fmaxf(acc.x, 0.f));
            p.y = f2bf(fmaxf(acc.y, 0.f));
            p.z = f2bf(fmaxf(acc.z, 0.f));
            p.w = f2bf(fmaxf(acc.w, 0.f));
            *(ushort4*)&Hout[rowOff + wid * 32 + ot * 16 + lhi * 4] = p;
        }
    }
}

// ---------------------------------------------------------------------------
// Pooling (proven R10)
// ---------------------------------------------------------------------------
__global__ __launch_bounds__(256) void pool_partial(const ushort* __restrict__ Hb,
                                                    const int* __restrict__ batch,
                                                    float* __restrict__ gsum) {
    int wave = (blockIdx.x * 256 + threadIdx.x) >> 6;
    int lane = threadIdx.x & 63;
    int base = wave * 64;
    if (base >= NNODES) return;
    int end = min(base + 64, NNODES);
    const uint* Hp = (const uint*)Hb + lane;
    float ax = 0.f, ay = 0.f;
    int gprev = batch[base];
    for (int n = base; n < end; ++n) {
        int g = batch[n];
        if (g != gprev) {
            atomicAdd(&gsum[gprev * DFEAT + lane * 2], ax);
            atomicAdd(&gsum[gprev * DFEAT + lane * 2 + 1], ay);
            ax = 0.f; ay = 0.f; gprev = g;
        }
        uint v = Hp[(size_t)n * 64];
        ax += __builtin_bit_cast(float, v << 16);
        ay += __builtin_bit_cast(float, v & 0xffff0000u);
    }
    atomicAdd(&gsum[gprev * DFEAT + lane * 2], ax);
    atomicAdd(&gsum[gprev * DFEAT + lane * 2 + 1], ay);
}

__global__ __launch_bounds__(128) void pool_classify2(const float* __restrict__ gsum,
                                                      const int* __restrict__ batch,
                                                      const float* __restrict__ Wc,
                                                      const float* __restrict__ bc,
                                                      float* __restrict__ out) {
    int g = blockIdx.x;
    int f = threadIdx.x;
    __shared__ int bounds[2];
    if (f < 2) {
        int target = g + f;
        int lo = 0, hi = NNODES;
        while (lo < hi) {
            int mid = (lo + hi) >> 1;
            if (batch[mid] < target) lo = mid + 1; else hi = mid;
        }
        bounds[f] = lo;
    }
    __syncthreads();
    float cnt = (float)(bounds[1] - bounds[0]);
    float pooled = gsum[g * DFEAT + f] / fmaxf(cnt, 1.0f);

    __shared__ float red[128];
    for (int o = 0; o < DOUTC; ++o) {
        red[f] = pooled * Wc[o * DFEAT + f];
        __syncthreads();
        for (int off = 64; off > 0; off >>= 1) {
            if (f < off) red[f] += red[f + off];
            __syncthreads();
        }
        if (f == 0) out[g * DOUTC + o] = red[0] + bc[o];
        __syncthreads();
    }
}

// ---------------------------------------------------------------------------
extern "C" void kernel_launch(void* const* d_in, const int* in_sizes, int n_in,
                              void* d_out, int out_size, void* d_ws, size_t ws_size,
                              hipStream_t stream) {
    const float* x    = (const float*)d_in[0];
    const int*   ei   = (const int*)d_in[1];
    const int*   batch= (const int*)d_in[2];
    const float* Wc   = (const float*)d_in[9];
    const float* bc   = (const float*)d_in[10];
    float* out = (float*)d_out;

    const int* rows = ei;            // edge_index[0] = dst (segment)
    const int* cols = ei + NEDGES;   // edge_index[1] = src (gather)

    // workspace carve-up
    char* ws = (char*)d_ws;
    ushort* Hb = (ushort*)ws;  ws += (size_t)NNODES * DFEAT * sizeof(ushort);
    ushort* Hc = (ushort*)ws;  ws += (size_t)NNODES * DFEAT * sizeof(ushort);
    ushort* Ab = (ushort*)ws;  ws += (size_t)NNODES * DFEAT * sizeof(ushort);
    ushort* Wb = (ushort*)ws;  ws += (size_t)6 * DFEAT * DFEAT * sizeof(ushort);
    float* gsum = (float*)ws;  ws += (size_t)NGRAPH * DFEAT * sizeof(float);
    int* deg    = (int*)ws;    ws += (size_t)NNODES * sizeof(int);
    int* offs   = (int*)ws;    ws += (size_t)NNODES * sizeof(int);
    int* cursor = (int*)ws;    ws += (size_t)NNODES * sizeof(int);
    int* scol   = (int*)ws;    ws += (size_t)NEDGES * sizeof(int);
    int* perm   = (int*)ws;    ws += (size_t)NNODES * sizeof(int);
    int* counter= (int*)ws;    ws += 64;
    int* binCnt = (int*)ws;    ws += NBINS * sizeof(int);
    int* binCur = (int*)ws;    ws += NBINS * sizeof(int);

    // 1) conversions + zero-init
    convert_all<<<784, 256, 0, stream>>>(x,
        (const float*)d_in[3], (const float*)d_in[4], (const float*)d_in[5],
        (const float*)d_in[6], (const float*)d_in[7], (const float*)d_in[8],
        Wb, Hb, gsum, deg, counter, binCnt);

    // 2) CSR build + degree binning
    const int nodeBlocks = (NNODES + 255) / 256;
    histo_kernel<<<(NEDGES + 255) / 256, 256, 0, stream>>>(rows, deg);
    alloc_ranges<<<nodeBlocks, 256, 0, stream>>>(deg, offs, cursor, counter);
    scatter_edges<<<(NEDGES + 255) / 256, 256, 0, stream>>>(rows, cols, cursor, scol);
    bin_count<<<nodeBlocks, 256, 0, stream>>>(deg, binCnt);
    bin_scan<<<1, 64, 0, stream>>>(binCnt, binCur);
    build_perm<<<nodeBlocks, 256, 0, stream>>>(deg, binCur, perm);

    // 3) three GNN layers
    const int aggGrid  = (NNODES + 15) / 16;
    const int gemmGrid = 1024;
    const ushort* hcur = Hb;
    ushort* hnext = Hc;
    for (int l = 0; l < 3; ++l) {
        const ushort* w1 = Wb + (size_t)(2 * l) * DFEAT * DFEAT;
        const ushort* w2 = Wb + (size_t)(2 * l + 1) * DFEAT * DFEAT;
        aggregate_g16<<<aggGrid, 256, 0, stream>>>(hcur, offs, deg, scol, perm, Ab);
        fused_dual_gemm_q<<<gemmGrid, 256, 0, stream>>>(hcur, Ab, w1, w2, hnext);
        const ushort* tmp = hcur; hcur = hnext; hnext = (ushort*)tmp;
    }

    // 4) pooling + classifier
    const int poolWaves = (NNODES + 63) / 64;
    pool_partial<<<(poolWaves * 64 + 255) / 256, 256, 0, stream>>>(hcur, batch, gsum);
    pool_classify2<<<NGRAPH, 128, 0, stream>>>(gsum, batch, Wc, bc, out);
}

// Round 17
// 302.491 us; speedup vs baseline: 1.0641x; 1.0641x over previous
//
#include <hip/hip_runtime.h>

#define NNODES 100000
#define NEDGES 625000
#define DFEAT  128
#define NGRAPH 256
#define DOUTC  10

typedef __attribute__((ext_vector_type(8))) short bf16x8;
typedef __attribute__((ext_vector_type(4))) float f32x4;
typedef __attribute__((ext_vector_type(8))) ushort ushort8v;

__device__ __forceinline__ ushort f2bf(float f) {
    __bf16 b = (__bf16)f;
    return __builtin_bit_cast(ushort, b);
}
__device__ __forceinline__ float bf2f(ushort u) {
    return __builtin_bit_cast(float, (uint)u << 16);
}

// ---------------------------------------------------------------------------
// convert_all: weights->bf16, x->bf16, zero gsum/deg/counter (proven R10)
// ---------------------------------------------------------------------------
__global__ __launch_bounds__(256) void convert_all(const float* __restrict__ x,
                                                   const float* __restrict__ w0,
                                                   const float* __restrict__ w1,
                                                   const float* __restrict__ w2,
                                                   const float* __restrict__ w3,
                                                   const float* __restrict__ w4,
                                                   const float* __restrict__ w5,
                                                   ushort* __restrict__ Wb,
                                                   ushort* __restrict__ Hb,
                                                   float* __restrict__ gsum,
                                                   int* __restrict__ deg,
                                                   int* __restrict__ counter) {
    const int tid = blockIdx.x * 256 + threadIdx.x;
    const int NT = gridDim.x * 256;
    if (tid == 0) *counter = 0;
    const float* ptrs[6] = {w0, w1, w2, w3, w4, w5};
    for (int i = tid; i < 6 * DFEAT * DFEAT; i += NT) {
        int m = i >> 14, j = i & 16383;
        Wb[i] = f2bf(ptrs[m][j]);
    }
    for (int i = tid; i < NGRAPH * DFEAT; i += NT) gsum[i] = 0.f;
    for (int i = tid; i < NNODES; i += NT) deg[i] = 0;
    const int n8 = NNODES * DFEAT / 8;
    for (int i = tid; i < n8; i += NT) {
        float4 a = *(const float4*)&x[(size_t)i * 8];
        float4 b = *(const float4*)&x[(size_t)i * 8 + 4];
        ushort8v o;
        o[0] = f2bf(a.x); o[1] = f2bf(a.y); o[2] = f2bf(a.z); o[3] = f2bf(a.w);
        o[4] = f2bf(b.x); o[5] = f2bf(b.y); o[6] = f2bf(b.z); o[7] = f2bf(b.w);
        *(ushort8v*)&Hb[(size_t)i * 8] = o;
    }
}

// ---------------------------------------------------------------------------
// CSR build, scan-free (proven R10)
// ---------------------------------------------------------------------------
__global__ __launch_bounds__(256) void histo_kernel(const int* __restrict__ rows,
                                                    int* __restrict__ deg) {
    int i = blockIdx.x * 256 + threadIdx.x;
    if (i < NEDGES) atomicAdd(&deg[rows[i]], 1);
}

__global__ __launch_bounds__(256) void alloc_ranges(const int* __restrict__ deg,
                                                    int* __restrict__ offs,
                                                    int* __restrict__ cursor,
                                                    int* __restrict__ counter) {
    __shared__ int red[256];
    __shared__ int baseSh;
    int t = threadIdx.x;
    int i = blockIdx.x * 256 + t;
    int v = (i < NNODES) ? deg[i] : 0;
    red[t] = v;
    __syncthreads();
    int x = v;
    for (int off = 1; off < 256; off <<= 1) {
        int y = (t >= off) ? red[t - off] : 0;
        __syncthreads();
        x += y;
        red[t] = x;
        __syncthreads();
    }
    if (t == 255) baseSh = atomicAdd(counter, x);
    __syncthreads();
    int pos = baseSh + x - v;
    if (i < NNODES) { offs[i] = pos; cursor[i] = pos; }
}

__global__ __launch_bounds__(256) void scatter_edges(const int* __restrict__ rows,
                                                     const int* __restrict__ cols,
                                                     int* __restrict__ cursor,
                                                     int* __restrict__ scol) {
    int i = blockIdx.x * 256 + threadIdx.x;
    if (i < NEDGES) {
        int p = atomicAdd(&cursor[rows[i]], 1);
        scol[p] = cols[i];
    }
}

// ---------------------------------------------------------------------------
// Aggregate in H-space (R13/R15 body, byte-identical): 16-lane group per
// node, 4 edge-rows in flight; 256 B coalesced row reads.
// ---------------------------------------------------------------------------
__global__ __launch_bounds__(256) void aggregate_g16(const ushort* __restrict__ Hb,
                                                     const int* __restrict__ offs,
                                                     const int* __restrict__ deg,
                                                     const int* __restrict__ scol,
                                                     ushort* __restrict__ Ab) {
    int node = blockIdx.x * 16 + (threadIdx.x >> 4);
    int l = threadIdx.x & 15;
    if (node >= NNODES) return;
    int beg = offs[node];
    int end = beg + deg[node];
    float a[8] = {};
    int e = beg;
    for (; e + 4 <= end; e += 4) {
        int c0 = scol[e];
        int c1 = scol[e + 1];
        int c2 = scol[e + 2];
        int c3 = scol[e + 3];
        ushort8v v0 = *(const ushort8v*)&Hb[(size_t)c0 * DFEAT + l * 8];
        ushort8v v1 = *(const ushort8v*)&Hb[(size_t)c1 * DFEAT + l * 8];
        ushort8v v2 = *(const ushort8v*)&Hb[(size_t)c2 * DFEAT + l * 8];
        ushort8v v3 = *(const ushort8v*)&Hb[(size_t)c3 * DFEAT + l * 8];
#pragma unroll
        for (int j = 0; j < 8; ++j)
            a[j] += (bf2f(v0[j]) + bf2f(v1[j])) + (bf2f(v2[j]) + bf2f(v3[j]));
    }
    for (; e < end; ++e) {
        int c0 = scol[e];
        ushort8v v0 = *(const ushort8v*)&Hb[(size_t)c0 * DFEAT + l * 8];
#pragma unroll
        for (int j = 0; j < 8; ++j) a[j] += bf2f(v0[j]);
    }
    ushort8v o;
#pragma unroll
    for (int j = 0; j < 8; ++j) o[j] = f2bf(a[j]);
    *(ushort8v*)&Ab[(size_t)node * DFEAT + l * 8] = o;
}

// ---------------------------------------------------------------------------
// Fused layer GEMM, quarter-split + reg-pinned weights + permuted W-row sets
// for coalesced 16 B stores:
//   tile ot's row-set: orow(i) = wid*32 + (i>>2)*8 + ot*4 + (i&3)
//   -> thread(lhi) gets feats wid*32+lhi*8+ot*4+{0..3}; ot=0,1 together are
//      8 contiguous feats -> ONE ushort8 store (16 rows x 64 B segments).
// Each output's dot product & order unchanged -> bit-identical to R15.
// ---------------------------------------------------------------------------
__global__ __launch_bounds__(256, 4) void fused_dual_gemm_q(const ushort* __restrict__ Hin,
                                                            const ushort* __restrict__ Ab,
                                                            const ushort* __restrict__ W1b,
                                                            const ushort* __restrict__ W2b,
                                                            ushort* __restrict__ Hout) {
    int wid = threadIdx.x >> 6;              // out-quarter 0..3
    int lane = threadIdx.x & 63;
    int l15 = lane & 15, lhi = lane >> 4;

    bf16x8 w1[2][4], w2[2][4];
#pragma unroll
    for (int ot = 0; ot < 2; ++ot)
#pragma unroll
        for (int ks = 0; ks < 4; ++ks) {
            int orow = wid * 32 + (l15 >> 2) * 8 + ot * 4 + (l15 & 3);
            w1[ot][ks] = *(const bf16x8*)&W1b[orow * DFEAT + ks * 32 + lhi * 8];
            w2[ot][ks] = *(const bf16x8*)&W2b[orow * DFEAT + ks * 32 + lhi * 8];
        }
#pragma unroll
    for (int ot = 0; ot < 2; ++ot)
#pragma unroll
        for (int ks = 0; ks < 4; ++ks) {
            asm volatile("" : "+v"(w1[ot][ks]));
            asm volatile("" : "+v"(w2[ot][ks]));
        }

    const int ntiles = NNODES / 16;              // 6250
    for (int t = blockIdx.x; t < ntiles; t += gridDim.x) {
        size_t rowOff = (size_t)(t * 16 + l15) * DFEAT;
        bf16x8 hfr[4], afr[4];
#pragma unroll
        for (int ks = 0; ks < 4; ++ks) {
            hfr[ks] = *(const bf16x8*)&Hin[rowOff + ks * 32 + lhi * 8];
            afr[ks] = *(const bf16x8*)&Ab[rowOff + ks * 32 + lhi * 8];
        }
        f32x4 acc0 = {}, acc1 = {};
#pragma unroll
        for (int ks = 0; ks < 4; ++ks)
            acc0 = __builtin_amdgcn_mfma_f32_16x16x32_bf16(w1[0][ks], hfr[ks], acc0, 0, 0, 0);
#pragma unroll
        for (int ks = 0; ks < 4; ++ks)
            acc0 = __builtin_amdgcn_mfma_f32_16x16x32_bf16(w2[0][ks], afr[ks], acc0, 0, 0, 0);
#pragma unroll
        for (int ks = 0; ks < 4; ++ks)
            acc1 = __builtin_amdgcn_mfma_f32_16x16x32_bf16(w1[1][ks], hfr[ks], acc1, 0, 0, 0);
#pragma unroll
        for (int ks = 0; ks < 4; ++ks)
            acc1 = __builtin_amdgcn_mfma_f32_16x16x32_bf16(w2[1][ks], afr[ks], acc1, 0, 0, 0);
        ushort8v p;
        p[0] = f2bf(fmaxf(acc0.x, 0.f));
        p[1] = f2bf(fmaxf(acc0.y, 0.f));
        p[2] = f2bf(fmaxf(acc0.z, 0.f));
        p[3] = f2bf(fmaxf(acc0.w, 0.f));
        p[4] = f2bf(fmaxf(acc1.x, 0.f));
        p[5] = f2bf(fmaxf(acc1.y, 0.f));
        p[6] = f2bf(fmaxf(acc1.z, 0.f));
        p[7] = f2bf(fmaxf(acc1.w, 0.f));
        *(ushort8v*)&Hout[rowOff + wid * 32 + lhi * 8] = p;
    }
}

// ---------------------------------------------------------------------------
// Pooling phase 1: per-graph feature sums (proven R10)
// ---------------------------------------------------------------------------
__global__ __launch_bounds__(256) void pool_partial(const ushort* __restrict__ Hb,
                                                    const int* __restrict__ batch,
                                                    float* __restrict__ gsum) {
    int wave = (blockIdx.x * 256 + threadIdx.x) >> 6;
    int lane = threadIdx.x & 63;
    int base = wave * 64;
    if (base >= NNODES) return;
    int end = min(base + 64, NNODES);
    const uint* Hp = (const uint*)Hb + lane;
    float ax = 0.f, ay = 0.f;
    int gprev = batch[base];
    for (int n = base; n < end; ++n) {
        int g = batch[n];
        if (g != gprev) {
            atomicAdd(&gsum[gprev * DFEAT + lane * 2], ax);
            atomicAdd(&gsum[gprev * DFEAT + lane * 2 + 1], ay);
            ax = 0.f; ay = 0.f; gprev = g;
        }
        uint v = Hp[(size_t)n * 64];
        ax += __builtin_bit_cast(float, v << 16);
        ay += __builtin_bit_cast(float, v & 0xffff0000u);
    }
    atomicAdd(&gsum[gprev * DFEAT + lane * 2], ax);
    atomicAdd(&gsum[gprev * DFEAT + lane * 2 + 1], ay);
}

// ---------------------------------------------------------------------------
// Pooling phase 2: divide by count, classify. (proven R10)
// ---------------------------------------------------------------------------
__global__ __launch_bounds__(128) void pool_classify2(const float* __restrict__ gsum,
                                                      const int* __restrict__ batch,
                                                      const float* __restrict__ Wc,
                                                      const float* __restrict__ bc,
                                                      float* __restrict__ out) {
    int g = blockIdx.x;
    int f = threadIdx.x;
    __shared__ int bounds[2];
    if (f < 2) {
        int target = g + f;
        int lo = 0, hi = NNODES;
        while (lo < hi) {
            int mid = (lo + hi) >> 1;
            if (batch[mid] < target) lo = mid + 1; else hi = mid;
        }
        bounds[f] = lo;
    }
    __syncthreads();
    float cnt = (float)(bounds[1] - bounds[0]);
    float pooled = gsum[g * DFEAT + f] / fmaxf(cnt, 1.0f);

    __shared__ float red[128];
    for (int o = 0; o < DOUTC; ++o) {
        red[f] = pooled * Wc[o * DFEAT + f];
        __syncthreads();
        for (int off = 64; off > 0; off >>= 1) {
            if (f < off) red[f] += red[f + off];
            __syncthreads();
        }
        if (f == 0) out[g * DOUTC + o] = red[0] + bc[o];
        __syncthreads();
    }
}

// ---------------------------------------------------------------------------
extern "C" void kernel_launch(void* const* d_in, const int* in_sizes, int n_in,
                              void* d_out, int out_size, void* d_ws, size_t ws_size,
                              hipStream_t stream) {
    const float* x    = (const float*)d_in[0];
    const int*   ei   = (const int*)d_in[1];
    const int*   batch= (const int*)d_in[2];
    const float* Wc   = (const float*)d_in[9];
    const float* bc   = (const float*)d_in[10];
    float* out = (float*)d_out;

    const int* rows = ei;            // edge_index[0] = dst (segment)
    const int* cols = ei + NEDGES;   // edge_index[1] = src (gather)

    // workspace carve-up
    char* ws = (char*)d_ws;
    ushort* Hb = (ushort*)ws;  ws += (size_t)NNODES * DFEAT * sizeof(ushort);
    ushort* Hc = (ushort*)ws;  ws += (size_t)NNODES * DFEAT * sizeof(ushort);
    ushort* Ab = (ushort*)ws;  ws += (size_t)NNODES * DFEAT * sizeof(ushort);
    ushort* Wb = (ushort*)ws;  ws += (size_t)6 * DFEAT * DFEAT * sizeof(ushort);
    float* gsum = (float*)ws;  ws += (size_t)NGRAPH * DFEAT * sizeof(float);
    int* deg    = (int*)ws;    ws += (size_t)NNODES * sizeof(int);
    int* offs   = (int*)ws;    ws += (size_t)NNODES * sizeof(int);
    int* cursor = (int*)ws;    ws += (size_t)NNODES * sizeof(int);
    int* scol   = (int*)ws;    ws += (size_t)NEDGES * sizeof(int);
    int* counter= (int*)ws;    ws += 64;

    // 1) conversions + zero-init
    convert_all<<<784, 256, 0, stream>>>(x,
        (const float*)d_in[3], (const float*)d_in[4], (const float*)d_in[5],
        (const float*)d_in[6], (const float*)d_in[7], (const float*)d_in[8],
        Wb, Hb, gsum, deg, counter);

    // 2) CSR build: histo -> alloc -> scatter
    histo_kernel<<<(NEDGES + 255) / 256, 256, 0, stream>>>(rows, deg);
    alloc_ranges<<<(NNODES + 255) / 256, 256, 0, stream>>>(deg, offs, cursor, counter);
    scatter_edges<<<(NEDGES + 255) / 256, 256, 0, stream>>>(rows, cols, cursor, scol);

    // 3) three GNN layers
    const int aggGrid  = (NNODES + 15) / 16;
    const int gemmGrid = 1024;               // 4 blocks/CU, ~6 tiles each
    const ushort* hcur = Hb;
    ushort* hnext = Hc;
    for (int l = 0; l < 3; ++l) {
        const ushort* w1 = Wb + (size_t)(2 * l) * DFEAT * DFEAT;
        const ushort* w2 = Wb + (size_t)(2 * l + 1) * DFEAT * DFEAT;
        aggregate_g16<<<aggGrid, 256, 0, stream>>>(hcur, offs, deg, scol, Ab);
        fused_dual_gemm_q<<<gemmGrid, 256, 0, stream>>>(hcur, Ab, w1, w2, hnext);
        const ushort* tmp = hcur; hcur = hnext; hnext = (ushort*)tmp;
    }

    // 4) pooling + classifier
    const int poolWaves = (NNODES + 63) / 64;
    pool_partial<<<(poolWaves * 64 + 255) / 256, 256, 0, stream>>>(hcur, batch, gsum);
    pool_classify2<<<NGRAPH, 128, 0, stream>>>(gsum, batch, Wc, bc, out);
}

// Round 18
// 260.302 us; speedup vs baseline: 1.2366x; 1.1621x over previous
//
#include <hip/hip_runtime.h>

#define NNODES 100000
#define NEDGES 625000
#define DFEAT  128
#define NGRAPH 256
#define DOUTC  10

typedef __attribute__((ext_vector_type(8))) short bf16x8;
typedef __attribute__((ext_vector_type(4))) float f32x4;
typedef __attribute__((ext_vector_type(8))) ushort ushort8v;

__device__ __forceinline__ ushort f2bf(float f) {
    __bf16 b = (__bf16)f;
    return __builtin_bit_cast(ushort, b);
}
__device__ __forceinline__ float bf2f(ushort u) {
    return __builtin_bit_cast(float, (uint)u << 16);
}

// ---------------------------------------------------------------------------
// convert_all: weights->bf16, x->bf16, zero gsum/deg/counter (proven R10)
// ---------------------------------------------------------------------------
__global__ __launch_bounds__(256) void convert_all(const float* __restrict__ x,
                                                   const float* __restrict__ w0,
                                                   const float* __restrict__ w1,
                                                   const float* __restrict__ w2,
                                                   const float* __restrict__ w3,
                                                   const float* __restrict__ w4,
                                                   const float* __restrict__ w5,
                                                   ushort* __restrict__ Wb,
                                                   ushort* __restrict__ Hb,
                                                   float* __restrict__ gsum,
                                                   int* __restrict__ deg,
                                                   int* __restrict__ counter) {
    const int tid = blockIdx.x * 256 + threadIdx.x;
    const int NT = gridDim.x * 256;
    if (tid == 0) *counter = 0;
    const float* ptrs[6] = {w0, w1, w2, w3, w4, w5};
    for (int i = tid; i < 6 * DFEAT * DFEAT; i += NT) {
        int m = i >> 14, j = i & 16383;
        Wb[i] = f2bf(ptrs[m][j]);
    }
    for (int i = tid; i < NGRAPH * DFEAT; i += NT) gsum[i] = 0.f;
    for (int i = tid; i < NNODES; i += NT) deg[i] = 0;
    const int n8 = NNODES * DFEAT / 8;
    for (int i = tid; i < n8; i += NT) {
        float4 a = *(const float4*)&x[(size_t)i * 8];
        float4 b = *(const float4*)&x[(size_t)i * 8 + 4];
        ushort8v o;
        o[0] = f2bf(a.x); o[1] = f2bf(a.y); o[2] = f2bf(a.z); o[3] = f2bf(a.w);
        o[4] = f2bf(b.x); o[5] = f2bf(b.y); o[6] = f2bf(b.z); o[7] = f2bf(b.w);
        *(ushort8v*)&Hb[(size_t)i * 8] = o;
    }
}

// ---------------------------------------------------------------------------
// CSR build, scan-free (proven R10)
// ---------------------------------------------------------------------------
__global__ __launch_bounds__(256) void histo_kernel(const int* __restrict__ rows,
                                                    int* __restrict__ deg) {
    int i = blockIdx.x * 256 + threadIdx.x;
    if (i < NEDGES) atomicAdd(&deg[rows[i]], 1);
}

__global__ __launch_bounds__(256) void alloc_ranges(const int* __restrict__ deg,
                                                    int* __restrict__ offs,
                                                    int* __restrict__ cursor,
                                                    int* __restrict__ counter) {
    __shared__ int red[256];
    __shared__ int baseSh;
    int t = threadIdx.x;
    int i = blockIdx.x * 256 + t;
    int v = (i < NNODES) ? deg[i] : 0;
    red[t] = v;
    __syncthreads();
    int x = v;
    for (int off = 1; off < 256; off <<= 1) {
        int y = (t >= off) ? red[t - off] : 0;
        __syncthreads();
        x += y;
        red[t] = x;
        __syncthreads();
    }
    if (t == 255) baseSh = atomicAdd(counter, x);
    __syncthreads();
    int pos = baseSh + x - v;
    if (i < NNODES) { offs[i] = pos; cursor[i] = pos; }
}

__global__ __launch_bounds__(256) void scatter_edges(const int* __restrict__ rows,
                                                     const int* __restrict__ cols,
                                                     int* __restrict__ cursor,
                                                     int* __restrict__ scol) {
    int i = blockIdx.x * 256 + threadIdx.x;
    if (i < NEDGES) {
        int p = atomicAdd(&cursor[rows[i]], 1);
        scol[p] = cols[i];
    }
}

// ---------------------------------------------------------------------------
// Aggregate in H-space (R13/R15 body, byte-identical): 16-lane group per
// node, 4 edge-rows in flight; 256 B coalesced row reads.
// ---------------------------------------------------------------------------
__global__ __launch_bounds__(256) void aggregate_g16(const ushort* __restrict__ Hb,
                                                     const int* __restrict__ offs,
                                                     const int* __restrict__ deg,
                                                     const int* __restrict__ scol,
                                                     ushort* __restrict__ Ab) {
    int node = blockIdx.x * 16 + (threadIdx.x >> 4);
    int l = threadIdx.x & 15;
    if (node >= NNODES) return;
    int beg = offs[node];
    int end = beg + deg[node];
    float a[8] = {};
    int e = beg;
    for (; e + 4 <= end; e += 4) {
        int c0 = scol[e];
        int c1 = scol[e + 1];
        int c2 = scol[e + 2];
        int c3 = scol[e + 3];
        ushort8v v0 = *(const ushort8v*)&Hb[(size_t)c0 * DFEAT + l * 8];
        ushort8v v1 = *(const ushort8v*)&Hb[(size_t)c1 * DFEAT + l * 8];
        ushort8v v2 = *(const ushort8v*)&Hb[(size_t)c2 * DFEAT + l * 8];
        ushort8v v3 = *(const ushort8v*)&Hb[(size_t)c3 * DFEAT + l * 8];
#pragma unroll
        for (int j = 0; j < 8; ++j)
            a[j] += (bf2f(v0[j]) + bf2f(v1[j])) + (bf2f(v2[j]) + bf2f(v3[j]));
    }
    for (; e < end; ++e) {
        int c0 = scol[e];
        ushort8v v0 = *(const ushort8v*)&Hb[(size_t)c0 * DFEAT + l * 8];
#pragma unroll
        for (int j = 0; j < 8; ++j) a[j] += bf2f(v0[j]);
    }
    ushort8v o;
#pragma unroll
    for (int j = 0; j < 8; ++j) o[j] = f2bf(a[j]);
    *(ushort8v*)&Ab[(size_t)node * DFEAT + l * 8] = o;
}

// ---------------------------------------------------------------------------
// Fused layer GEMM, LDS-staged tile + quarter-split + pinned/permuted weights:
// The 8 KB H/A tile is loaded from global ONCE per block (cooperative, 16 B
// per thread, XOR-swizzled byte ^= (row&7)<<4) and all 4 waves read their
// MFMA fragments from LDS -> eliminates the 4x per-CU L1 redundancy of the
// register version. ds_read_b128 at stride 256 B would be a 16-way bank
// conflict; the XOR swizzle makes it 2-way (free, m136).
// Same fragments, same MFMA order -> bit-identical to R17.
// ---------------------------------------------------------------------------
__global__ __launch_bounds__(256, 3) void fused_dual_gemm_lds(const ushort* __restrict__ Hin,
                                                              const ushort* __restrict__ Ab,
                                                              const ushort* __restrict__ W1b,
                                                              const ushort* __restrict__ W2b,
                                                              ushort* __restrict__ Hout) {
    __shared__ char lds[8192];          // [0,4096) = H tile, [4096,8192) = A tile
    const int tid = threadIdx.x;
    const int wid = tid >> 6;           // out-quarter 0..3
    const int lane = tid & 63;
    const int l15 = lane & 15, lhi = lane >> 4;

    // weights: permuted row-set (R17) so ot=0,1 give 8 contiguous out-feats
    bf16x8 w1[2][4], w2[2][4];
#pragma unroll
    for (int ot = 0; ot < 2; ++ot)
#pragma unroll
        for (int ks = 0; ks < 4; ++ks) {
            int orow = wid * 32 + (l15 >> 2) * 8 + ot * 4 + (l15 & 3);
            w1[ot][ks] = *(const bf16x8*)&W1b[orow * DFEAT + ks * 32 + lhi * 8];
            w2[ot][ks] = *(const bf16x8*)&W2b[orow * DFEAT + ks * 32 + lhi * 8];
        }
#pragma unroll
    for (int ot = 0; ot < 2; ++ot)
#pragma unroll
        for (int ks = 0; ks < 4; ++ks) {
            asm volatile("" : "+v"(w1[ot][ks]));
            asm volatile("" : "+v"(w2[ot][ks]));
        }

    // staging indices: thread t loads row sr, 16 B chunk sj (coalesced 1 KB/wave)
    const int sr = tid >> 4;            // 0..15
    const int sj = (tid & 15) * 16;     // byte chunk within 256 B row
    const int swz = sj ^ ((sr & 7) << 4);
    // fragment read offsets (per lane), swizzled
    int roff[4];
#pragma unroll
    for (int ks = 0; ks < 4; ++ks)
        roff[ks] = l15 * 256 + ((ks * 64 + lhi * 16) ^ ((l15 & 7) << 4));

    const int ntiles = NNODES / 16;     // 6250
    for (int t = blockIdx.x; t < ntiles; t += gridDim.x) {
        size_t tileByte = (size_t)t * 16 * 256;
        ushort8v hv = *(const ushort8v*)((const char*)Hin + tileByte + sr * 256 + sj);
        ushort8v av = *(const ushort8v*)((const char*)Ab + tileByte + sr * 256 + sj);
        __syncthreads();                // prev iteration's LDS reads complete
        *(ushort8v*)&lds[sr * 256 + swz] = hv;
        *(ushort8v*)&lds[4096 + sr * 256 + swz] = av;
        __syncthreads();                // tile ready

        bf16x8 hfr[4], afr[4];
#pragma unroll
        for (int ks = 0; ks < 4; ++ks) {
            hfr[ks] = *(const bf16x8*)&lds[roff[ks]];
            afr[ks] = *(const bf16x8*)&lds[4096 + roff[ks]];
        }
        f32x4 acc0 = {}, acc1 = {};
#pragma unroll
        for (int ks = 0; ks < 4; ++ks)
            acc0 = __builtin_amdgcn_mfma_f32_16x16x32_bf16(w1[0][ks], hfr[ks], acc0, 0, 0, 0);
#pragma unroll
        for (int ks = 0; ks < 4; ++ks)
            acc0 = __builtin_amdgcn_mfma_f32_16x16x32_bf16(w2[0][ks], afr[ks], acc0, 0, 0, 0);
#pragma unroll
        for (int ks = 0; ks < 4; ++ks)
            acc1 = __builtin_amdgcn_mfma_f32_16x16x32_bf16(w1[1][ks], hfr[ks], acc1, 0, 0, 0);
#pragma unroll
        for (int ks = 0; ks < 4; ++ks)
            acc1 = __builtin_amdgcn_mfma_f32_16x16x32_bf16(w2[1][ks], afr[ks], acc1, 0, 0, 0);
        ushort8v p;
        p[0] = f2bf(fmaxf(acc0.x, 0.f));
        p[1] = f2bf(fmaxf(acc0.y, 0.f));
        p[2] = f2bf(fmaxf(acc0.z, 0.f));
        p[3] = f2bf(fmaxf(acc0.w, 0.f));
        p[4] = f2bf(fmaxf(acc1.x, 0.f));
        p[5] = f2bf(fmaxf(acc1.y, 0.f));
        p[6] = f2bf(fmaxf(acc1.z, 0.f));
        p[7] = f2bf(fmaxf(acc1.w, 0.f));
        *(ushort8v*)&Hout[(size_t)(t * 16 + l15) * DFEAT + wid * 32 + lhi * 8] = p;
    }
}

// ---------------------------------------------------------------------------
// Pooling phase 1: per-graph feature sums (proven R10)
// ---------------------------------------------------------------------------
__global__ __launch_bounds__(256) void pool_partial(const ushort* __restrict__ Hb,
                                                    const int* __restrict__ batch,
                                                    float* __restrict__ gsum) {
    int wave = (blockIdx.x * 256 + threadIdx.x) >> 6;
    int lane = threadIdx.x & 63;
    int base = wave * 64;
    if (base >= NNODES) return;
    int end = min(base + 64, NNODES);
    const uint* Hp = (const uint*)Hb + lane;
    float ax = 0.f, ay = 0.f;
    int gprev = batch[base];
    for (int n = base; n < end; ++n) {
        int g = batch[n];
        if (g != gprev) {
            atomicAdd(&gsum[gprev * DFEAT + lane * 2], ax);
            atomicAdd(&gsum[gprev * DFEAT + lane * 2 + 1], ay);
            ax = 0.f; ay = 0.f; gprev = g;
        }
        uint v = Hp[(size_t)n * 64];
        ax += __builtin_bit_cast(float, v << 16);
        ay += __builtin_bit_cast(float, v & 0xffff0000u);
    }
    atomicAdd(&gsum[gprev * DFEAT + lane * 2], ax);
    atomicAdd(&gsum[gprev * DFEAT + lane * 2 + 1], ay);
}

// ---------------------------------------------------------------------------
// Pooling phase 2: divide by count, classify. (proven R10)
// ---------------------------------------------------------------------------
__global__ __launch_bounds__(128) void pool_classify2(const float* __restrict__ gsum,
                                                      const int* __restrict__ batch,
                                                      const float* __restrict__ Wc,
                                                      const float* __restrict__ bc,
                                                      float* __restrict__ out) {
    int g = blockIdx.x;
    int f = threadIdx.x;
    __shared__ int bounds[2];
    if (f < 2) {
        int target = g + f;
        int lo = 0, hi = NNODES;
        while (lo < hi) {
            int mid = (lo + hi) >> 1;
            if (batch[mid] < target) lo = mid + 1; else hi = mid;
        }
        bounds[f] = lo;
    }
    __syncthreads();
    float cnt = (float)(bounds[1] - bounds[0]);
    float pooled = gsum[g * DFEAT + f] / fmaxf(cnt, 1.0f);

    __shared__ float red[128];
    for (int o = 0; o < DOUTC; ++o) {
        red[f] = pooled * Wc[o * DFEAT + f];
        __syncthreads();
        for (int off = 64; off > 0; off >>= 1) {
            if (f < off) red[f] += red[f + off];
            __syncthreads();
        }
        if (f == 0) out[g * DOUTC + o] = red[0] + bc[o];
        __syncthreads();
    }
}

// ---------------------------------------------------------------------------
extern "C" void kernel_launch(void* const* d_in, const int* in_sizes, int n_in,
                              void* d_out, int out_size, void* d_ws, size_t ws_size,
                              hipStream_t stream) {
    const float* x    = (const float*)d_in[0];
    const int*   ei   = (const int*)d_in[1];
    const int*   batch= (const int*)d_in[2];
    const float* Wc   = (const float*)d_in[9];
    const float* bc   = (const float*)d_in[10];
    float* out = (float*)d_out;

    const int* rows = ei;            // edge_index[0] = dst (segment)
    const int* cols = ei + NEDGES;   // edge_index[1] = src (gather)

    // workspace carve-up
    char* ws = (char*)d_ws;
    ushort* Hb = (ushort*)ws;  ws += (size_t)NNODES * DFEAT * sizeof(ushort);
    ushort* Hc = (ushort*)ws;  ws += (size_t)NNODES * DFEAT * sizeof(ushort);
    ushort* Ab = (ushort*)ws;  ws += (size_t)NNODES * DFEAT * sizeof(ushort);
    ushort* Wb = (ushort*)ws;  ws += (size_t)6 * DFEAT * DFEAT * sizeof(ushort);
    float* gsum = (float*)ws;  ws += (size_t)NGRAPH * DFEAT * sizeof(float);
    int* deg    = (int*)ws;    ws += (size_t)NNODES * sizeof(int);
    int* offs   = (int*)ws;    ws += (size_t)NNODES * sizeof(int);
    int* cursor = (int*)ws;    ws += (size_t)NNODES * sizeof(int);
    int* scol   = (int*)ws;    ws += (size_t)NEDGES * sizeof(int);
    int* counter= (int*)ws;    ws += 64;

    // 1) conversions + zero-init
    convert_all<<<784, 256, 0, stream>>>(x,
        (const float*)d_in[3], (const float*)d_in[4], (const float*)d_in[5],
        (const float*)d_in[6], (const float*)d_in[7], (const float*)d_in[8],
        Wb, Hb, gsum, deg, counter);

    // 2) CSR build: histo -> alloc -> scatter
    histo_kernel<<<(NEDGES + 255) / 256, 256, 0, stream>>>(rows, deg);
    alloc_ranges<<<(NNODES + 255) / 256, 256, 0, stream>>>(deg, offs, cursor, counter);
    scatter_edges<<<(NEDGES + 255) / 256, 256, 0, stream>>>(rows, cols, cursor, scol);

    // 3) three GNN layers
    const int aggGrid  = (NNODES + 15) / 16;
    const int gemmGrid = 768;            // 3 blocks/CU exact, ~8 tiles each
    const ushort* hcur = Hb;
    ushort* hnext = Hc;
    for (int l = 0; l < 3; ++l) {
        const ushort* w1 = Wb + (size_t)(2 * l) * DFEAT * DFEAT;
        const ushort* w2 = Wb + (size_t)(2 * l + 1) * DFEAT * DFEAT;
        aggregate_g16<<<aggGrid, 256, 0, stream>>>(hcur, offs, deg, scol, Ab);
        fused_dual_gemm_lds<<<gemmGrid, 256, 0, stream>>>(hcur, Ab, w1, w2, hnext);
        const ushort* tmp = hcur; hcur = hnext; hnext = (ushort*)tmp;
    }

    // 4) pooling + classifier
    const int poolWaves = (NNODES + 63) / 64;
    pool_partial<<<(poolWaves * 64 + 255) / 256, 256, 0, stream>>>(hcur, batch, gsum);
    pool_classify2<<<NGRAPH, 128, 0, stream>>>(gsum, batch, Wc, bc, out);
}

// Round 19
// 258.975 us; speedup vs baseline: 1.2429x; 1.0051x over previous
//
#include <hip/hip_runtime.h>

#define NNODES 100000
#define NEDGES 625000
#define DFEAT  128
#define NGRAPH 256
#define DOUTC  10

typedef __attribute__((ext_vector_type(8))) short bf16x8;
typedef __attribute__((ext_vector_type(4))) float f32x4;
typedef __attribute__((ext_vector_type(8))) ushort ushort8v;

__device__ __forceinline__ ushort f2bf(float f) {
    __bf16 b = (__bf16)f;
    return __builtin_bit_cast(ushort, b);
}
__device__ __forceinline__ float bf2f(ushort u) {
    return __builtin_bit_cast(float, (uint)u << 16);
}

// ---------------------------------------------------------------------------
// convert_all: weights->bf16, x->bf16, zero gsum/deg/counter (proven R10)
// ---------------------------------------------------------------------------
__global__ __launch_bounds__(256) void convert_all(const float* __restrict__ x,
                                                   const float* __restrict__ w0,
                                                   const float* __restrict__ w1,
                                                   const float* __restrict__ w2,
                                                   const float* __restrict__ w3,
                                                   const float* __restrict__ w4,
                                                   const float* __restrict__ w5,
                                                   ushort* __restrict__ Wb,
                                                   ushort* __restrict__ Hb,
                                                   float* __restrict__ gsum,
                                                   int* __restrict__ deg,
                                                   int* __restrict__ counter) {
    const int tid = blockIdx.x * 256 + threadIdx.x;
    const int NT = gridDim.x * 256;
    if (tid == 0) *counter = 0;
    const float* ptrs[6] = {w0, w1, w2, w3, w4, w5};
    for (int i = tid; i < 6 * DFEAT * DFEAT; i += NT) {
        int m = i >> 14, j = i & 16383;
        Wb[i] = f2bf(ptrs[m][j]);
    }
    for (int i = tid; i < NGRAPH * DFEAT; i += NT) gsum[i] = 0.f;
    for (int i = tid; i < NNODES; i += NT) deg[i] = 0;
    const int n8 = NNODES * DFEAT / 8;
    for (int i = tid; i < n8; i += NT) {
        float4 a = *(const float4*)&x[(size_t)i * 8];
        float4 b = *(const float4*)&x[(size_t)i * 8 + 4];
        ushort8v o;
        o[0] = f2bf(a.x); o[1] = f2bf(a.y); o[2] = f2bf(a.z); o[3] = f2bf(a.w);
        o[4] = f2bf(b.x); o[5] = f2bf(b.y); o[6] = f2bf(b.z); o[7] = f2bf(b.w);
        *(ushort8v*)&Hb[(size_t)i * 8] = o;
    }
}

// ---------------------------------------------------------------------------
// CSR build, scan-free (proven R10)
// ---------------------------------------------------------------------------
__global__ __launch_bounds__(256) void histo_kernel(const int* __restrict__ rows,
                                                    int* __restrict__ deg) {
    int i = blockIdx.x * 256 + threadIdx.x;
    if (i < NEDGES) atomicAdd(&deg[rows[i]], 1);
}

__global__ __launch_bounds__(256) void alloc_ranges(const int* __restrict__ deg,
                                                    int* __restrict__ offs,
                                                    int* __restrict__ cursor,
                                                    int* __restrict__ counter) {
    __shared__ int red[256];
    __shared__ int baseSh;
    int t = threadIdx.x;
    int i = blockIdx.x * 256 + t;
    int v = (i < NNODES) ? deg[i] : 0;
    red[t] = v;
    __syncthreads();
    int x = v;
    for (int off = 1; off < 256; off <<= 1) {
        int y = (t >= off) ? red[t - off] : 0;
        __syncthreads();
        x += y;
        red[t] = x;
        __syncthreads();
    }
    if (t == 255) baseSh = atomicAdd(counter, x);
    __syncthreads();
    int pos = baseSh + x - v;
    if (i < NNODES) { offs[i] = pos; cursor[i] = pos; }
}

__global__ __launch_bounds__(256) void scatter_edges(const int* __restrict__ rows,
                                                     const int* __restrict__ cols,
                                                     int* __restrict__ cursor,
                                                     int* __restrict__ scol) {
    int i = blockIdx.x * 256 + threadIdx.x;
    if (i < NEDGES) {
        int p = atomicAdd(&cursor[rows[i]], 1);
        scol[p] = cols[i];
    }
}

// ---------------------------------------------------------------------------
// Aggregate in H-space (R13/R15 body, byte-identical)
// ---------------------------------------------------------------------------
__global__ __launch_bounds__(256) void aggregate_g16(const ushort* __restrict__ Hb,
                                                     const int* __restrict__ offs,
                                                     const int* __restrict__ deg,
                                                     const int* __restrict__ scol,
                                                     ushort* __restrict__ Ab) {
    int node = blockIdx.x * 16 + (threadIdx.x >> 4);
    int l = threadIdx.x & 15;
    if (node >= NNODES) return;
    int beg = offs[node];
    int end = beg + deg[node];
    float a[8] = {};
    int e = beg;
    for (; e + 4 <= end; e += 4) {
        int c0 = scol[e];
        int c1 = scol[e + 1];
        int c2 = scol[e + 2];
        int c3 = scol[e + 3];
        ushort8v v0 = *(const ushort8v*)&Hb[(size_t)c0 * DFEAT + l * 8];
        ushort8v v1 = *(const ushort8v*)&Hb[(size_t)c1 * DFEAT + l * 8];
        ushort8v v2 = *(const ushort8v*)&Hb[(size_t)c2 * DFEAT + l * 8];
        ushort8v v3 = *(const ushort8v*)&Hb[(size_t)c3 * DFEAT + l * 8];
#pragma unroll
        for (int j = 0; j < 8; ++j)
            a[j] += (bf2f(v0[j]) + bf2f(v1[j])) + (bf2f(v2[j]) + bf2f(v3[j]));
    }
    for (; e < end; ++e) {
        int c0 = scol[e];
        ushort8v v0 = *(const ushort8v*)&Hb[(size_t)c0 * DFEAT + l * 8];
#pragma unroll
        for (int j = 0; j < 8; ++j) a[j] += bf2f(v0[j]);
    }
    ushort8v o;
#pragma unroll
    for (int j = 0; j < 8; ++j) o[j] = f2bf(a[j]);
    *(ushort8v*)&Ab[(size_t)node * DFEAT + l * 8] = o;
}

// ---------------------------------------------------------------------------
// Fused layer GEMM, LDS-staged tile (proven R18, byte-identical)
// ---------------------------------------------------------------------------
__global__ __launch_bounds__(256, 3) void fused_dual_gemm_lds(const ushort* __restrict__ Hin,
                                                              const ushort* __restrict__ Ab,
                                                              const ushort* __restrict__ W1b,
                                                              const ushort* __restrict__ W2b,
                                                              ushort* __restrict__ Hout) {
    __shared__ char lds[8192];
    const int tid = threadIdx.x;
    const int wid = tid >> 6;
    const int lane = tid & 63;
    const int l15 = lane & 15, lhi = lane >> 4;

    bf16x8 w1[2][4], w2[2][4];
#pragma unroll
    for (int ot = 0; ot < 2; ++ot)
#pragma unroll
        for (int ks = 0; ks < 4; ++ks) {
            int orow = wid * 32 + (l15 >> 2) * 8 + ot * 4 + (l15 & 3);
            w1[ot][ks] = *(const bf16x8*)&W1b[orow * DFEAT + ks * 32 + lhi * 8];
            w2[ot][ks] = *(const bf16x8*)&W2b[orow * DFEAT + ks * 32 + lhi * 8];
        }
#pragma unroll
    for (int ot = 0; ot < 2; ++ot)
#pragma unroll
        for (int ks = 0; ks < 4; ++ks) {
            asm volatile("" : "+v"(w1[ot][ks]));
            asm volatile("" : "+v"(w2[ot][ks]));
        }

    const int sr = tid >> 4;
    const int sj = (tid & 15) * 16;
    const int swz = sj ^ ((sr & 7) << 4);
    int roff[4];
#pragma unroll
    for (int ks = 0; ks < 4; ++ks)
        roff[ks] = l15 * 256 + ((ks * 64 + lhi * 16) ^ ((l15 & 7) << 4));

    const int ntiles = NNODES / 16;
    for (int t = blockIdx.x; t < ntiles; t += gridDim.x) {
        size_t tileByte = (size_t)t * 16 * 256;
        ushort8v hv = *(const ushort8v*)((const char*)Hin + tileByte + sr * 256 + sj);
        ushort8v av = *(const ushort8v*)((const char*)Ab + tileByte + sr * 256 + sj);
        __syncthreads();
        *(ushort8v*)&lds[sr * 256 + swz] = hv;
        *(ushort8v*)&lds[4096 + sr * 256 + swz] = av;
        __syncthreads();

        bf16x8 hfr[4], afr[4];
#pragma unroll
        for (int ks = 0; ks < 4; ++ks) {
            hfr[ks] = *(const bf16x8*)&lds[roff[ks]];
            afr[ks] = *(const bf16x8*)&lds[4096 + roff[ks]];
        }
        f32x4 acc0 = {}, acc1 = {};
#pragma unroll
        for (int ks = 0; ks < 4; ++ks)
            acc0 = __builtin_amdgcn_mfma_f32_16x16x32_bf16(w1[0][ks], hfr[ks], acc0, 0, 0, 0);
#pragma unroll
        for (int ks = 0; ks < 4; ++ks)
            acc0 = __builtin_amdgcn_mfma_f32_16x16x32_bf16(w2[0][ks], afr[ks], acc0, 0, 0, 0);
#pragma unroll
        for (int ks = 0; ks < 4; ++ks)
            acc1 = __builtin_amdgcn_mfma_f32_16x16x32_bf16(w1[1][ks], hfr[ks], acc1, 0, 0, 0);
#pragma unroll
        for (int ks = 0; ks < 4; ++ks)
            acc1 = __builtin_amdgcn_mfma_f32_16x16x32_bf16(w2[1][ks], afr[ks], acc1, 0, 0, 0);
        ushort8v p;
        p[0] = f2bf(fmaxf(acc0.x, 0.f));
        p[1] = f2bf(fmaxf(acc0.y, 0.f));
        p[2] = f2bf(fmaxf(acc0.z, 0.f));
        p[3] = f2bf(fmaxf(acc0.w, 0.f));
        p[4] = f2bf(fmaxf(acc1.x, 0.f));
        p[5] = f2bf(fmaxf(acc1.y, 0.f));
        p[6] = f2bf(fmaxf(acc1.z, 0.f));
        p[7] = f2bf(fmaxf(acc1.w, 0.f));
        *(ushort8v*)&Hout[(size_t)(t * 16 + l15) * DFEAT + wid * 32 + lhi * 8] = p;
    }
}

// ---------------------------------------------------------------------------
// Last layer: GEMM + pooling fused. Same GEMM body as R18; instead of writing
// H3, each 16-lane group (same 8 contiguous feats x 16 nodes) does a masked
// butterfly reduce per graph-run (batch sorted -> >=1 runs/tile, usually 1)
// and the run-leader lane atomically adds 8 f32 values to gsum. Saves the
// 25.6 MB H3 write + 25.6 MB pool read + one dispatch.
// ---------------------------------------------------------------------------
__global__ __launch_bounds__(256, 3) void fused_dual_gemm_lds_pool(
        const ushort* __restrict__ Hin,
        const ushort* __restrict__ Ab,
        const ushort* __restrict__ W1b,
        const ushort* __restrict__ W2b,
        const int* __restrict__ batch,
        float* __restrict__ gsum) {
    __shared__ char lds[8192];
    const int tid = threadIdx.x;
    const int wid = tid >> 6;
    const int lane = tid & 63;
    const int l15 = lane & 15, lhi = lane >> 4;
    const int f0 = wid * 32 + lhi * 8;       // this lane's 8 contiguous feats

    bf16x8 w1[2][4], w2[2][4];
#pragma unroll
    for (int ot = 0; ot < 2; ++ot)
#pragma unroll
        for (int ks = 0; ks < 4; ++ks) {
            int orow = wid * 32 + (l15 >> 2) * 8 + ot * 4 + (l15 & 3);
            w1[ot][ks] = *(const bf16x8*)&W1b[orow * DFEAT + ks * 32 + lhi * 8];
            w2[ot][ks] = *(const bf16x8*)&W2b[orow * DFEAT + ks * 32 + lhi * 8];
        }
#pragma unroll
    for (int ot = 0; ot < 2; ++ot)
#pragma unroll
        for (int ks = 0; ks < 4; ++ks) {
            asm volatile("" : "+v"(w1[ot][ks]));
            asm volatile("" : "+v"(w2[ot][ks]));
        }

    const int sr = tid >> 4;
    const int sj = (tid & 15) * 16;
    const int swz = sj ^ ((sr & 7) << 4);
    int roff[4];
#pragma unroll
    for (int ks = 0; ks < 4; ++ks)
        roff[ks] = l15 * 256 + ((ks * 64 + lhi * 16) ^ ((l15 & 7) << 4));

    const int ntiles = NNODES / 16;
    for (int t = blockIdx.x; t < ntiles; t += gridDim.x) {
        size_t tileByte = (size_t)t * 16 * 256;
        ushort8v hv = *(const ushort8v*)((const char*)Hin + tileByte + sr * 256 + sj);
        ushort8v av = *(const ushort8v*)((const char*)Ab + tileByte + sr * 256 + sj);
        __syncthreads();
        *(ushort8v*)&lds[sr * 256 + swz] = hv;
        *(ushort8v*)&lds[4096 + sr * 256 + swz] = av;
        __syncthreads();

        bf16x8 hfr[4], afr[4];
#pragma unroll
        for (int ks = 0; ks < 4; ++ks) {
            hfr[ks] = *(const bf16x8*)&lds[roff[ks]];
            afr[ks] = *(const bf16x8*)&lds[4096 + roff[ks]];
        }
        f32x4 acc0 = {}, acc1 = {};
#pragma unroll
        for (int ks = 0; ks < 4; ++ks)
            acc0 = __builtin_amdgcn_mfma_f32_16x16x32_bf16(w1[0][ks], hfr[ks], acc0, 0, 0, 0);
#pragma unroll
        for (int ks = 0; ks < 4; ++ks)
            acc0 = __builtin_amdgcn_mfma_f32_16x16x32_bf16(w2[0][ks], afr[ks], acc0, 0, 0, 0);
#pragma unroll
        for (int ks = 0; ks < 4; ++ks)
            acc1 = __builtin_amdgcn_mfma_f32_16x16x32_bf16(w1[1][ks], hfr[ks], acc1, 0, 0, 0);
#pragma unroll
        for (int ks = 0; ks < 4; ++ks)
            acc1 = __builtin_amdgcn_mfma_f32_16x16x32_bf16(w2[1][ks], afr[ks], acc1, 0, 0, 0);

        // relu, match the bf16 rounding of the stored-H3 path
        float v0 = bf2f(f2bf(fmaxf(acc0.x, 0.f)));
        float v1 = bf2f(f2bf(fmaxf(acc0.y, 0.f)));
        float v2 = bf2f(f2bf(fmaxf(acc0.z, 0.f)));
        float v3 = bf2f(f2bf(fmaxf(acc0.w, 0.f)));
        float v4 = bf2f(f2bf(fmaxf(acc1.x, 0.f)));
        float v5 = bf2f(f2bf(fmaxf(acc1.y, 0.f)));
        float v6 = bf2f(f2bf(fmaxf(acc1.z, 0.f)));
        float v7 = bf2f(f2bf(fmaxf(acc1.w, 0.f)));

        int g = batch[t * 16 + l15];          // same pattern in all 4 groups
        int remaining = 0xFFFF;               // unflushed l15 lanes
        while (remaining) {
            int lead = __ffs(remaining) - 1;
            int gl = __shfl(g, (lane & 48) | lead, 64);
            bool mine = (g == gl);
            float s0 = mine ? v0 : 0.f, s1 = mine ? v1 : 0.f;
            float s2 = mine ? v2 : 0.f, s3 = mine ? v3 : 0.f;
            float s4 = mine ? v4 : 0.f, s5 = mine ? v5 : 0.f;
            float s6 = mine ? v6 : 0.f, s7 = mine ? v7 : 0.f;
#pragma unroll
            for (int off = 1; off < 16; off <<= 1) {
                s0 += __shfl_xor(s0, off, 64);
                s1 += __shfl_xor(s1, off, 64);
                s2 += __shfl_xor(s2, off, 64);
                s3 += __shfl_xor(s3, off, 64);
                s4 += __shfl_xor(s4, off, 64);
                s5 += __shfl_xor(s5, off, 64);
                s6 += __shfl_xor(s6, off, 64);
                s7 += __shfl_xor(s7, off, 64);
            }
            if (l15 == lead) {
                float* gp = &gsum[gl * DFEAT + f0];
                atomicAdd(gp + 0, s0);
                atomicAdd(gp + 1, s1);
                atomicAdd(gp + 2, s2);
                atomicAdd(gp + 3, s3);
                atomicAdd(gp + 4, s4);
                atomicAdd(gp + 5, s5);
                atomicAdd(gp + 6, s6);
                atomicAdd(gp + 7, s7);
            }
            remaining &= ~((int)(__ballot(mine) & 0xFFFFull));
        }
    }
}

// ---------------------------------------------------------------------------
// Pooling phase 2: divide by count, classify. (proven R10)
// ---------------------------------------------------------------------------
__global__ __launch_bounds__(128) void pool_classify2(const float* __restrict__ gsum,
                                                      const int* __restrict__ batch,
                                                      const float* __restrict__ Wc,
                                                      const float* __restrict__ bc,
                                                      float* __restrict__ out) {
    int g = blockIdx.x;
    int f = threadIdx.x;
    __shared__ int bounds[2];
    if (f < 2) {
        int target = g + f;
        int lo = 0, hi = NNODES;
        while (lo < hi) {
            int mid = (lo + hi) >> 1;
            if (batch[mid] < target) lo = mid + 1; else hi = mid;
        }
        bounds[f] = lo;
    }
    __syncthreads();
    float cnt = (float)(bounds[1] - bounds[0]);
    float pooled = gsum[g * DFEAT + f] / fmaxf(cnt, 1.0f);

    __shared__ float red[128];
    for (int o = 0; o < DOUTC; ++o) {
        red[f] = pooled * Wc[o * DFEAT + f];
        __syncthreads();
        for (int off = 64; off > 0; off >>= 1) {
            if (f < off) red[f] += red[f + off];
            __syncthreads();
        }
        if (f == 0) out[g * DOUTC + o] = red[0] + bc[o];
        __syncthreads();
    }
}

// ---------------------------------------------------------------------------
extern "C" void kernel_launch(void* const* d_in, const int* in_sizes, int n_in,
                              void* d_out, int out_size, void* d_ws, size_t ws_size,
                              hipStream_t stream) {
    const float* x    = (const float*)d_in[0];
    const int*   ei   = (const int*)d_in[1];
    const int*   batch= (const int*)d_in[2];
    const float* Wc   = (const float*)d_in[9];
    const float* bc   = (const float*)d_in[10];
    float* out = (float*)d_out;

    const int* rows = ei;            // edge_index[0] = dst (segment)
    const int* cols = ei + NEDGES;   // edge_index[1] = src (gather)

    // workspace carve-up
    char* ws = (char*)d_ws;
    ushort* Hb = (ushort*)ws;  ws += (size_t)NNODES * DFEAT * sizeof(ushort);
    ushort* Hc = (ushort*)ws;  ws += (size_t)NNODES * DFEAT * sizeof(ushort);
    ushort* Ab = (ushort*)ws;  ws += (size_t)NNODES * DFEAT * sizeof(ushort);
    ushort* Wb = (ushort*)ws;  ws += (size_t)6 * DFEAT * DFEAT * sizeof(ushort);
    float* gsum = (float*)ws;  ws += (size_t)NGRAPH * DFEAT * sizeof(float);
    int* deg    = (int*)ws;    ws += (size_t)NNODES * sizeof(int);
    int* offs   = (int*)ws;    ws += (size_t)NNODES * sizeof(int);
    int* cursor = (int*)ws;    ws += (size_t)NNODES * sizeof(int);
    int* scol   = (int*)ws;    ws += (size_t)NEDGES * sizeof(int);
    int* counter= (int*)ws;    ws += 64;

    // 1) conversions + zero-init
    convert_all<<<784, 256, 0, stream>>>(x,
        (const float*)d_in[3], (const float*)d_in[4], (const float*)d_in[5],
        (const float*)d_in[6], (const float*)d_in[7], (const float*)d_in[8],
        Wb, Hb, gsum, deg, counter);

    // 2) CSR build: histo -> alloc -> scatter
    histo_kernel<<<(NEDGES + 255) / 256, 256, 0, stream>>>(rows, deg);
    alloc_ranges<<<(NNODES + 255) / 256, 256, 0, stream>>>(deg, offs, cursor, counter);
    scatter_edges<<<(NEDGES + 255) / 256, 256, 0, stream>>>(rows, cols, cursor, scol);

    // 3) three GNN layers; layer 2's GEMM also pools (H3 never materialized)
    const int aggGrid  = (NNODES + 15) / 16;
    const int gemmGrid = 768;            // 3 blocks/CU exact
    const ushort* hcur = Hb;
    ushort* hnext = Hc;
    for (int l = 0; l < 2; ++l) {
        const ushort* w1 = Wb + (size_t)(2 * l) * DFEAT * DFEAT;
        const ushort* w2 = Wb + (size_t)(2 * l + 1) * DFEAT * DFEAT;
        aggregate_g16<<<aggGrid, 256, 0, stream>>>(hcur, offs, deg, scol, Ab);
        fused_dual_gemm_lds<<<gemmGrid, 256, 0, stream>>>(hcur, Ab, w1, w2, hnext);
        const ushort* tmp = hcur; hcur = hnext; hnext = (ushort*)tmp;
    }
    {
        const ushort* w1 = Wb + (size_t)4 * DFEAT * DFEAT;
        const ushort* w2 = Wb + (size_t)5 * DFEAT * DFEAT;
        aggregate_g16<<<aggGrid, 256, 0, stream>>>(hcur, offs, deg, scol, Ab);
        fused_dual_gemm_lds_pool<<<gemmGrid, 256, 0, stream>>>(hcur, Ab, w1, w2, batch, gsum);
    }

    // 4) classifier
    pool_classify2<<<NGRAPH, 128, 0, stream>>>(gsum, batch, Wc, bc, out);
}

// Round 20
// 236.258 us; speedup vs baseline: 1.3624x; 1.0962x over previous
//
#include <hip/hip_runtime.h>

#define NNODES 100000
#define NEDGES 625000
#define DFEAT  128
#define NGRAPH 256
#define DOUTC  10

typedef __attribute__((ext_vector_type(8))) short bf16x8;
typedef __attribute__((ext_vector_type(4))) float f32x4;
typedef __attribute__((ext_vector_type(8))) ushort ushort8v;

__device__ __forceinline__ ushort f2bf(float f) {
    __bf16 b = (__bf16)f;
    return __builtin_bit_cast(ushort, b);
}
__device__ __forceinline__ float bf2f(ushort u) {
    return __builtin_bit_cast(float, (uint)u << 16);
}

// ---------------------------------------------------------------------------
// convert_all: weights->bf16, x->bf16, zero gsum/deg/counter (proven R10)
// ---------------------------------------------------------------------------
__global__ __launch_bounds__(256) void convert_all(const float* __restrict__ x,
                                                   const float* __restrict__ w0,
                                                   const float* __restrict__ w1,
                                                   const float* __restrict__ w2,
                                                   const float* __restrict__ w3,
                                                   const float* __restrict__ w4,
                                                   const float* __restrict__ w5,
                                                   ushort* __restrict__ Wb,
                                                   ushort* __restrict__ Hb,
                                                   float* __restrict__ gsum,
                                                   int* __restrict__ deg,
                                                   int* __restrict__ counter) {
    const int tid = blockIdx.x * 256 + threadIdx.x;
    const int NT = gridDim.x * 256;
    if (tid == 0) *counter = 0;
    const float* ptrs[6] = {w0, w1, w2, w3, w4, w5};
    for (int i = tid; i < 6 * DFEAT * DFEAT; i += NT) {
        int m = i >> 14, j = i & 16383;
        Wb[i] = f2bf(ptrs[m][j]);
    }
    for (int i = tid; i < NGRAPH * DFEAT; i += NT) gsum[i] = 0.f;
    for (int i = tid; i < NNODES; i += NT) deg[i] = 0;
    const int n8 = NNODES * DFEAT / 8;
    for (int i = tid; i < n8; i += NT) {
        float4 a = *(const float4*)&x[(size_t)i * 8];
        float4 b = *(const float4*)&x[(size_t)i * 8 + 4];
        ushort8v o;
        o[0] = f2bf(a.x); o[1] = f2bf(a.y); o[2] = f2bf(a.z); o[3] = f2bf(a.w);
        o[4] = f2bf(b.x); o[5] = f2bf(b.y); o[6] = f2bf(b.z); o[7] = f2bf(b.w);
        *(ushort8v*)&Hb[(size_t)i * 8] = o;
    }
}

// ---------------------------------------------------------------------------
// CSR build, scan-free (proven R10)
// ---------------------------------------------------------------------------
__global__ __launch_bounds__(256) void histo_kernel(const int* __restrict__ rows,
                                                    int* __restrict__ deg) {
    int i = blockIdx.x * 256 + threadIdx.x;
    if (i < NEDGES) atomicAdd(&deg[rows[i]], 1);
}

__global__ __launch_bounds__(256) void alloc_ranges(const int* __restrict__ deg,
                                                    int* __restrict__ offs,
                                                    int* __restrict__ cursor,
                                                    int* __restrict__ counter) {
    __shared__ int red[256];
    __shared__ int baseSh;
    int t = threadIdx.x;
    int i = blockIdx.x * 256 + t;
    int v = (i < NNODES) ? deg[i] : 0;
    red[t] = v;
    __syncthreads();
    int x = v;
    for (int off = 1; off < 256; off <<= 1) {
        int y = (t >= off) ? red[t - off] : 0;
        __syncthreads();
        x += y;
        red[t] = x;
        __syncthreads();
    }
    if (t == 255) baseSh = atomicAdd(counter, x);
    __syncthreads();
    int pos = baseSh + x - v;
    if (i < NNODES) { offs[i] = pos; cursor[i] = pos; }
}

__global__ __launch_bounds__(256) void scatter_edges(const int* __restrict__ rows,
                                                     const int* __restrict__ cols,
                                                     int* __restrict__ cursor,
                                                     int* __restrict__ scol) {
    int i = blockIdx.x * 256 + threadIdx.x;
    if (i < NEDGES) {
        int p = atomicAdd(&cursor[rows[i]], 1);
        scol[p] = cols[i];
    }
}

// ---------------------------------------------------------------------------
// Aggregate in H-space (R13/R15 body, byte-identical)
// ---------------------------------------------------------------------------
__global__ __launch_bounds__(256) void aggregate_g16(const ushort* __restrict__ Hb,
                                                     const int* __restrict__ offs,
                                                     const int* __restrict__ deg,
                                                     const int* __restrict__ scol,
                                                     ushort* __restrict__ Ab) {
    int node = blockIdx.x * 16 + (threadIdx.x >> 4);
    int l = threadIdx.x & 15;
    if (node >= NNODES) return;
    int beg = offs[node];
    int end = beg + deg[node];
    float a[8] = {};
    int e = beg;
    for (; e + 4 <= end; e += 4) {
        int c0 = scol[e];
        int c1 = scol[e + 1];
        int c2 = scol[e + 2];
        int c3 = scol[e + 3];
        ushort8v v0 = *(const ushort8v*)&Hb[(size_t)c0 * DFEAT + l * 8];
        ushort8v v1 = *(const ushort8v*)&Hb[(size_t)c1 * DFEAT + l * 8];
        ushort8v v2 = *(const ushort8v*)&Hb[(size_t)c2 * DFEAT + l * 8];
        ushort8v v3 = *(const ushort8v*)&Hb[(size_t)c3 * DFEAT + l * 8];
#pragma unroll
        for (int j = 0; j < 8; ++j)
            a[j] += (bf2f(v0[j]) + bf2f(v1[j])) + (bf2f(v2[j]) + bf2f(v3[j]));
    }
    for (; e < end; ++e) {
        int c0 = scol[e];
        ushort8v v0 = *(const ushort8v*)&Hb[(size_t)c0 * DFEAT + l * 8];
#pragma unroll
        for (int j = 0; j < 8; ++j) a[j] += bf2f(v0[j]);
    }
    ushort8v o;
#pragma unroll
    for (int j = 0; j < 8; ++j) o[j] = f2bf(a[j]);
    *(ushort8v*)&Ab[(size_t)node * DFEAT + l * 8] = o;
}

// ---------------------------------------------------------------------------
// Fused layer GEMM, LDS-staged tile (proven R18, byte-identical)
// ---------------------------------------------------------------------------
__global__ __launch_bounds__(256, 3) void fused_dual_gemm_lds(const ushort* __restrict__ Hin,
                                                              const ushort* __restrict__ Ab,
                                                              const ushort* __restrict__ W1b,
                                                              const ushort* __restrict__ W2b,
                                                              ushort* __restrict__ Hout) {
    __shared__ char lds[8192];
    const int tid = threadIdx.x;
    const int wid = tid >> 6;
    const int lane = tid & 63;
    const int l15 = lane & 15, lhi = lane >> 4;

    bf16x8 w1[2][4], w2[2][4];
#pragma unroll
    for (int ot = 0; ot < 2; ++ot)
#pragma unroll
        for (int ks = 0; ks < 4; ++ks) {
            int orow = wid * 32 + (l15 >> 2) * 8 + ot * 4 + (l15 & 3);
            w1[ot][ks] = *(const bf16x8*)&W1b[orow * DFEAT + ks * 32 + lhi * 8];
            w2[ot][ks] = *(const bf16x8*)&W2b[orow * DFEAT + ks * 32 + lhi * 8];
        }
#pragma unroll
    for (int ot = 0; ot < 2; ++ot)
#pragma unroll
        for (int ks = 0; ks < 4; ++ks) {
            asm volatile("" : "+v"(w1[ot][ks]));
            asm volatile("" : "+v"(w2[ot][ks]));
        }

    const int sr = tid >> 4;
    const int sj = (tid & 15) * 16;
    const int swz = sj ^ ((sr & 7) << 4);
    int roff[4];
#pragma unroll
    for (int ks = 0; ks < 4; ++ks)
        roff[ks] = l15 * 256 + ((ks * 64 + lhi * 16) ^ ((l15 & 7) << 4));

    const int ntiles = NNODES / 16;
    for (int t = blockIdx.x; t < ntiles; t += gridDim.x) {
        size_t tileByte = (size_t)t * 16 * 256;
        ushort8v hv = *(const ushort8v*)((const char*)Hin + tileByte + sr * 256 + sj);
        ushort8v av = *(const ushort8v*)((const char*)Ab + tileByte + sr * 256 + sj);
        __syncthreads();
        *(ushort8v*)&lds[sr * 256 + swz] = hv;
        *(ushort8v*)&lds[4096 + sr * 256 + swz] = av;
        __syncthreads();

        bf16x8 hfr[4], afr[4];
#pragma unroll
        for (int ks = 0; ks < 4; ++ks) {
            hfr[ks] = *(const bf16x8*)&lds[roff[ks]];
            afr[ks] = *(const bf16x8*)&lds[4096 + roff[ks]];
        }
        f32x4 acc0 = {}, acc1 = {};
#pragma unroll
        for (int ks = 0; ks < 4; ++ks)
            acc0 = __builtin_amdgcn_mfma_f32_16x16x32_bf16(w1[0][ks], hfr[ks], acc0, 0, 0, 0);
#pragma unroll
        for (int ks = 0; ks < 4; ++ks)
            acc0 = __builtin_amdgcn_mfma_f32_16x16x32_bf16(w2[0][ks], afr[ks], acc0, 0, 0, 0);
#pragma unroll
        for (int ks = 0; ks < 4; ++ks)
            acc1 = __builtin_amdgcn_mfma_f32_16x16x32_bf16(w1[1][ks], hfr[ks], acc1, 0, 0, 0);
#pragma unroll
        for (int ks = 0; ks < 4; ++ks)
            acc1 = __builtin_amdgcn_mfma_f32_16x16x32_bf16(w2[1][ks], afr[ks], acc1, 0, 0, 0);
        ushort8v p;
        p[0] = f2bf(fmaxf(acc0.x, 0.f));
        p[1] = f2bf(fmaxf(acc0.y, 0.f));
        p[2] = f2bf(fmaxf(acc0.z, 0.f));
        p[3] = f2bf(fmaxf(acc0.w, 0.f));
        p[4] = f2bf(fmaxf(acc1.x, 0.f));
        p[5] = f2bf(fmaxf(acc1.y, 0.f));
        p[6] = f2bf(fmaxf(acc1.z, 0.f));
        p[7] = f2bf(fmaxf(acc1.w, 0.f));
        *(ushort8v*)&Hout[(size_t)(t * 16 + l15) * DFEAT + wid * 32 + lhi * 8] = p;
    }
}

// ---------------------------------------------------------------------------
// Last layer: GEMM + pooling fused, CONTIGUOUS tile ranges + lazy flush.
// Block b owns tiles [b*nt/nb, (b+1)*nt/nb): lane's node steps by 16/tile so
// its graph changes rarely (~0.4 boundaries/block). Per-lane running sums
// (8 f32) + gcur; the masked-run butterfly + leader atomics run only when
// __any(g != gcur) (wave-uniform: all 4 groups share the node set) and once
// at the end -> ~1.4 flushes/block instead of 9 (R19's per-tile cost).
// ---------------------------------------------------------------------------
__global__ __launch_bounds__(256, 3) void fused_dual_gemm_lds_pool(
        const ushort* __restrict__ Hin,
        const ushort* __restrict__ Ab,
        const ushort* __restrict__ W1b,
        const ushort* __restrict__ W2b,
        const int* __restrict__ batch,
        float* __restrict__ gsum) {
    __shared__ char lds[8192];
    const int tid = threadIdx.x;
    const int wid = tid >> 6;
    const int lane = tid & 63;
    const int l15 = lane & 15, lhi = lane >> 4;
    const int f0 = wid * 32 + lhi * 8;

    bf16x8 w1[2][4], w2[2][4];
#pragma unroll
    for (int ot = 0; ot < 2; ++ot)
#pragma unroll
        for (int ks = 0; ks < 4; ++ks) {
            int orow = wid * 32 + (l15 >> 2) * 8 + ot * 4 + (l15 & 3);
            w1[ot][ks] = *(const bf16x8*)&W1b[orow * DFEAT + ks * 32 + lhi * 8];
            w2[ot][ks] = *(const bf16x8*)&W2b[orow * DFEAT + ks * 32 + lhi * 8];
        }
#pragma unroll
    for (int ot = 0; ot < 2; ++ot)
#pragma unroll
        for (int ks = 0; ks < 4; ++ks) {
            asm volatile("" : "+v"(w1[ot][ks]));
            asm volatile("" : "+v"(w2[ot][ks]));
        }

    const int sr = tid >> 4;
    const int sj = (tid & 15) * 16;
    const int swz = sj ^ ((sr & 7) << 4);
    int roff[4];
#pragma unroll
    for (int ks = 0; ks < 4; ++ks)
        roff[ks] = l15 * 256 + ((ks * 64 + lhi * 16) ^ ((l15 & 7) << 4));

    const int ntiles = NNODES / 16;
    const int tBeg = (int)(((long)blockIdx.x * ntiles) / gridDim.x);
    const int tEnd = (int)(((long)(blockIdx.x + 1) * ntiles) / gridDim.x);
    if (tBeg >= tEnd) return;

    float s[8] = {};
    int gcur = batch[tBeg * 16 + l15];

    auto flush = [&]() {
        int remaining = 0xFFFF;
        while (remaining) {
            int lead = __ffs(remaining) - 1;
            int gl = __shfl(gcur, (lane & 48) | lead, 64);
            bool mine = (gcur == gl);
            float r[8];
#pragma unroll
            for (int j = 0; j < 8; ++j) r[j] = mine ? s[j] : 0.f;
#pragma unroll
            for (int off = 1; off < 16; off <<= 1)
#pragma unroll
                for (int j = 0; j < 8; ++j) r[j] += __shfl_xor(r[j], off, 64);
            if (l15 == lead) {
                float* gp = &gsum[gl * DFEAT + f0];
#pragma unroll
                for (int j = 0; j < 8; ++j) atomicAdd(gp + j, r[j]);
            }
            remaining &= ~((int)(__ballot(mine) & 0xFFFFull));
        }
    };

    for (int t = tBeg; t < tEnd; ++t) {
        size_t tileByte = (size_t)t * 16 * 256;
        ushort8v hv = *(const ushort8v*)((const char*)Hin + tileByte + sr * 256 + sj);
        ushort8v av = *(const ushort8v*)((const char*)Ab + tileByte + sr * 256 + sj);
        __syncthreads();
        *(ushort8v*)&lds[sr * 256 + swz] = hv;
        *(ushort8v*)&lds[4096 + sr * 256 + swz] = av;
        __syncthreads();

        bf16x8 hfr[4], afr[4];
#pragma unroll
        for (int ks = 0; ks < 4; ++ks) {
            hfr[ks] = *(const bf16x8*)&lds[roff[ks]];
            afr[ks] = *(const bf16x8*)&lds[4096 + roff[ks]];
        }
        f32x4 acc0 = {}, acc1 = {};
#pragma unroll
        for (int ks = 0; ks < 4; ++ks)
            acc0 = __builtin_amdgcn_mfma_f32_16x16x32_bf16(w1[0][ks], hfr[ks], acc0, 0, 0, 0);
#pragma unroll
        for (int ks = 0; ks < 4; ++ks)
            acc0 = __builtin_amdgcn_mfma_f32_16x16x32_bf16(w2[0][ks], afr[ks], acc0, 0, 0, 0);
#pragma unroll
        for (int ks = 0; ks < 4; ++ks)
            acc1 = __builtin_amdgcn_mfma_f32_16x16x32_bf16(w1[1][ks], hfr[ks], acc1, 0, 0, 0);
#pragma unroll
        for (int ks = 0; ks < 4; ++ks)
            acc1 = __builtin_amdgcn_mfma_f32_16x16x32_bf16(w2[1][ks], afr[ks], acc1, 0, 0, 0);

        int g = batch[t * 16 + l15];
        if (__any(g != gcur)) {
            flush();
#pragma unroll
            for (int j = 0; j < 8; ++j) s[j] = 0.f;
            gcur = g;
        }
        // relu + bf16-rounding to match the stored-H3 path
        s[0] += bf2f(f2bf(fmaxf(acc0.x, 0.f)));
        s[1] += bf2f(f2bf(fmaxf(acc0.y, 0.f)));
        s[2] += bf2f(f2bf(fmaxf(acc0.z, 0.f)));
        s[3] += bf2f(f2bf(fmaxf(acc0.w, 0.f)));
        s[4] += bf2f(f2bf(fmaxf(acc1.x, 0.f)));
        s[5] += bf2f(f2bf(fmaxf(acc1.y, 0.f)));
        s[6] += bf2f(f2bf(fmaxf(acc1.z, 0.f)));
        s[7] += bf2f(f2bf(fmaxf(acc1.w, 0.f)));
    }
    flush();
}

// ---------------------------------------------------------------------------
// Pooling phase 2: divide by count, classify. (proven R10)
// ---------------------------------------------------------------------------
__global__ __launch_bounds__(128) void pool_classify2(const float* __restrict__ gsum,
                                                      const int* __restrict__ batch,
                                                      const float* __restrict__ Wc,
                                                      const float* __restrict__ bc,
                                                      float* __restrict__ out) {
    int g = blockIdx.x;
    int f = threadIdx.x;
    __shared__ int bounds[2];
    if (f < 2) {
        int target = g + f;
        int lo = 0, hi = NNODES;
        while (lo < hi) {
            int mid = (lo + hi) >> 1;
            if (batch[mid] < target) lo = mid + 1; else hi = mid;
        }
        bounds[f] = lo;
    }
    __syncthreads();
    float cnt = (float)(bounds[1] - bounds[0]);
    float pooled = gsum[g * DFEAT + f] / fmaxf(cnt, 1.0f);

    __shared__ float red[128];
    for (int o = 0; o < DOUTC; ++o) {
        red[f] = pooled * Wc[o * DFEAT + f];
        __syncthreads();
        for (int off = 64; off > 0; off >>= 1) {
            if (f < off) red[f] += red[f + off];
            __syncthreads();
        }
        if (f == 0) out[g * DOUTC + o] = red[0] + bc[o];
        __syncthreads();
    }
}

// ---------------------------------------------------------------------------
extern "C" void kernel_launch(void* const* d_in, const int* in_sizes, int n_in,
                              void* d_out, int out_size, void* d_ws, size_t ws_size,
                              hipStream_t stream) {
    const float* x    = (const float*)d_in[0];
    const int*   ei   = (const int*)d_in[1];
    const int*   batch= (const int*)d_in[2];
    const float* Wc   = (const float*)d_in[9];
    const float* bc   = (const float*)d_in[10];
    float* out = (float*)d_out;

    const int* rows = ei;            // edge_index[0] = dst (segment)
    const int* cols = ei + NEDGES;   // edge_index[1] = src (gather)

    // workspace carve-up
    char* ws = (char*)d_ws;
    ushort* Hb = (ushort*)ws;  ws += (size_t)NNODES * DFEAT * sizeof(ushort);
    ushort* Hc = (ushort*)ws;  ws += (size_t)NNODES * DFEAT * sizeof(ushort);
    ushort* Ab = (ushort*)ws;  ws += (size_t)NNODES * DFEAT * sizeof(ushort);
    ushort* Wb = (ushort*)ws;  ws += (size_t)6 * DFEAT * DFEAT * sizeof(ushort);
    float* gsum = (float*)ws;  ws += (size_t)NGRAPH * DFEAT * sizeof(float);
    int* deg    = (int*)ws;    ws += (size_t)NNODES * sizeof(int);
    int* offs   = (int*)ws;    ws += (size_t)NNODES * sizeof(int);
    int* cursor = (int*)ws;    ws += (size_t)NNODES * sizeof(int);
    int* scol   = (int*)ws;    ws += (size_t)NEDGES * sizeof(int);
    int* counter= (int*)ws;    ws += 64;

    // 1) conversions + zero-init
    convert_all<<<784, 256, 0, stream>>>(x,
        (const float*)d_in[3], (const float*)d_in[4], (const float*)d_in[5],
        (const float*)d_in[6], (const float*)d_in[7], (const float*)d_in[8],
        Wb, Hb, gsum, deg, counter);

    // 2) CSR build: histo -> alloc -> scatter
    histo_kernel<<<(NEDGES + 255) / 256, 256, 0, stream>>>(rows, deg);
    alloc_ranges<<<(NNODES + 255) / 256, 256, 0, stream>>>(deg, offs, cursor, counter);
    scatter_edges<<<(NEDGES + 255) / 256, 256, 0, stream>>>(rows, cols, cursor, scol);

    // 3) three GNN layers; layer 2's GEMM also pools (H3 never materialized)
    const int aggGrid  = (NNODES + 15) / 16;
    const int gemmGrid = 768;            // 3 blocks/CU exact
    const ushort* hcur = Hb;
    ushort* hnext = Hc;
    for (int l = 0; l < 2; ++l) {
        const ushort* w1 = Wb + (size_t)(2 * l) * DFEAT * DFEAT;
        const ushort* w2 = Wb + (size_t)(2 * l + 1) * DFEAT * DFEAT;
        aggregate_g16<<<aggGrid, 256, 0, stream>>>(hcur, offs, deg, scol, Ab);
        fused_dual_gemm_lds<<<gemmGrid, 256, 0, stream>>>(hcur, Ab, w1, w2, hnext);
        const ushort* tmp = hcur; hcur = hnext; hnext = (ushort*)tmp;
    }
    {
        const ushort* w1 = Wb + (size_t)4 * DFEAT * DFEAT;
        const ushort* w2 = Wb + (size_t)5 * DFEAT * DFEAT;
        aggregate_g16<<<aggGrid, 256, 0, stream>>>(hcur, offs, deg, scol, Ab);
        fused_dual_gemm_lds_pool<<<gemmGrid, 256, 0, stream>>>(hcur, Ab, w1, w2, batch, gsum);
    }

    // 4) classifier
    pool_classify2<<<NGRAPH, 128, 0, stream>>>(gsum, batch, Wc, bc, out);
}